// Round 5
// baseline (93.691 us; speedup 1.0000x reference)
//
#include <hip/hip_runtime.h>
#include <hip/hip_bf16.h>

// Problem constants
#define B_ 4
#define S_ 4096
#define H_ 1024
#define D_ 64
#define CHUNK 64
#define NCHUNK (S_ / CHUNK)

typedef short bf16x8 __attribute__((ext_vector_type(8)));
typedef short bf16x4 __attribute__((ext_vector_type(4)));
typedef float f32x4 __attribute__((ext_vector_type(4)));

__device__ inline unsigned short f2bf(float f) {
    union { float f; unsigned u; } v; v.f = f;
    return (unsigned short)((v.u + 0x7fffu + ((v.u >> 16) & 1u)) >> 16);
}
__device__ inline float bf2f(unsigned short u) {
    union { unsigned u; float f; } v; v.u = (unsigned)u << 16;
    return v.f;
}
__device__ inline bf16x8 cvt8(const float4& a, const float4& b) {
    bf16x8 r;
    r[0] = (short)f2bf(a.x); r[1] = (short)f2bf(a.y);
    r[2] = (short)f2bf(a.z); r[3] = (short)f2bf(a.w);
    r[4] = (short)f2bf(b.x); r[5] = (short)f2bf(b.y);
    r[6] = (short)f2bf(b.z); r[7] = (short)f2bf(b.w);
    return r;
}

// ---------- PROVEN: prep_w ----------
__global__ void prep_w(const float* __restrict__ Wk, const float* __restrict__ Wv,
                       unsigned short* __restrict__ WkT, unsigned short* __restrict__ WvT) {
    int gid = blockIdx.x * 256 + threadIdx.x;  // gid = d*H + h
    int d = gid >> 10;
    int h = gid & (H_ - 1);
    WkT[gid] = f2bf(Wk[h * D_ + d]);
    WvT[gid] = f2bf(Wv[h * D_ + d]);
}

// ---------- kv_moment6: 1024 thr, 4sv x 4hv waves, per-iter barrier for L1 dedup ----------
__global__ __launch_bounds__(1024)
void kv_moment6(const float* __restrict__ x, const unsigned short* __restrict__ WkT,
                const unsigned short* __restrict__ WvT, unsigned short* __restrict__ pMb) {
    int blk = blockIdx.x;            // 0..255, 64 blocks per batch
    int b = blk >> 6;
    int s0 = (blk & 63) * 64;
    int tid = threadIdx.x;
    int w = tid >> 6;                // wave 0..15
    int sv = w >> 2;                 // s-subtile 0..3 (16 rows each)
    int hv = w & 3;                  // H-slice 0..3 (256 each)
    int lane = tid & 63;
    int r = lane & 15, kg = lane >> 4;

    __shared__ float pbuf[2][4][16][68];      // 34816 B, reused 4x (K g0, K g1, V g0, V g1)
    __shared__ unsigned short Klds[64][68];   // 8704 B
    __shared__ unsigned short Vlds[64][68];   // 8704 B   -> 52224 B total

    f32x4 accK[4] = {}, accV[4] = {};
    const float* xrow = x + ((size_t)b * S_ + s0 + sv * 16 + r) * H_ + hv * 256;

    for (int it = 0; it < 8; ++it) {
        __syncthreads();  // keep the 4 same-hv waves temporally aligned -> L1 hits
        int kb = it * 32 + kg * 8;
        float4 a0 = *(const float4*)(xrow + kb);
        float4 a1 = *(const float4*)(xrow + kb + 4);
        bf16x8 af = cvt8(a0, a1);
        int kglob = hv * 256 + kb;
#pragma unroll
        for (int nt = 0; nt < 4; ++nt) {
            bf16x8 bk = *(const bf16x8*)(WkT + (nt * 16 + r) * H_ + kglob);
            bf16x8 bv = *(const bf16x8*)(WvT + (nt * 16 + r) * H_ + kglob);
            accK[nt] = __builtin_amdgcn_mfma_f32_16x16x32_bf16(af, bk, accK[nt], 0, 0, 0);
            accV[nt] = __builtin_amdgcn_mfma_f32_16x16x32_bf16(af, bv, accV[nt], 0, 0, 0);
        }
    }

    // ---- 4-phase cross-hv reduce (pbuf is 32 rows; phase over sv-pairs), K then V ----
    int rw = (tid >> 4) & 31;        // 0..31 (used when tid < 512)
    int c4 = tid & 15;
#pragma unroll
    for (int g = 0; g < 2; ++g) {    // K phases
        if ((sv >> 1) == g) {
#pragma unroll
            for (int nt = 0; nt < 4; ++nt)
#pragma unroll
                for (int i = 0; i < 4; ++i)
                    pbuf[sv & 1][hv][kg * 4 + i][nt * 16 + r] = accK[nt][i];
        }
        __syncthreads();
        if (tid < 512) {
            f32x4 s = *(const f32x4*)&pbuf[rw >> 4][0][rw & 15][c4 * 4];
#pragma unroll
            for (int hh = 1; hh < 4; ++hh)
                s += *(const f32x4*)&pbuf[rw >> 4][hh][rw & 15][c4 * 4];
            bf16x4 p4;
#pragma unroll
            for (int j = 0; j < 4; ++j) p4[j] = (short)f2bf(s[j]);
            *(bf16x4*)&Klds[g * 32 + rw][c4 * 4] = p4;
        }
        __syncthreads();
    }
#pragma unroll
    for (int g = 0; g < 2; ++g) {    // V phases
        if ((sv >> 1) == g) {
#pragma unroll
            for (int nt = 0; nt < 4; ++nt)
#pragma unroll
                for (int i = 0; i < 4; ++i)
                    pbuf[sv & 1][hv][kg * 4 + i][nt * 16 + r] = accV[nt][i];
        }
        __syncthreads();
        if (tid < 512) {
            f32x4 s = *(const f32x4*)&pbuf[rw >> 4][0][rw & 15][c4 * 4];
#pragma unroll
            for (int hh = 1; hh < 4; ++hh)
                s += *(const f32x4*)&pbuf[rw >> 4][hh][rw & 15][c4 * 4];
            bf16x4 p4;
#pragma unroll
            for (int j = 0; j < 4; ++j) p4[j] = (short)f2bf(s[j]);
            *(bf16x4*)&Vlds[g * 32 + rw][c4 * 4] = p4;
        }
        __syncthreads();
    }

    // ---- Stage 2: Mpart[e][d] = sum_{s<64} K[s][e]*V[s][d]; wave w -> tile (et, dh) ----
    int et = w & 3, dh = w >> 2;
    f32x4 accM = {};
#pragma unroll
    for (int ks = 0; ks < 2; ++ks) {
        bf16x8 afm, bfm;
#pragma unroll
        for (int i = 0; i < 8; ++i) {
            afm[i] = (short)Klds[ks * 32 + kg * 8 + i][et * 16 + r];
            bfm[i] = (short)Vlds[ks * 32 + kg * 8 + i][dh * 16 + r];
        }
        accM = __builtin_amdgcn_mfma_f32_16x16x32_bf16(afm, bfm, accM, 0, 0, 0);
    }
    unsigned short* outp = pMb + (size_t)blk * 4096;
#pragma unroll
    for (int i = 0; i < 4; ++i)
        outp[(et * 16 + kg * 4 + i) * 64 + dh * 16 + r] = f2bf(accM[i]);
}

// ---------- reduce_m6: 64 bf16 partials per batch ----------
__global__ void reduce_m6(const unsigned short* __restrict__ pMb, float* __restrict__ M) {
    int gid = blockIdx.x * 256 + threadIdx.x;  // 0..16383
    int b = gid >> 12;
    int idx = gid & 4095;
    const unsigned short* p = pMb + (size_t)b * 64 * 4096 + idx;
    float a0 = 0.f, a1 = 0.f, a2 = 0.f, a3 = 0.f;
#pragma unroll 2
    for (int c = 0; c < 64; c += 4) {
        a0 += bf2f(p[(size_t)(c + 0) * 4096]);
        a1 += bf2f(p[(size_t)(c + 1) * 4096]);
        a2 += bf2f(p[(size_t)(c + 2) * 4096]);
        a3 += bf2f(p[(size_t)(c + 3) * 4096]);
    }
    M[gid] = (a0 + a1) + (a2 + a3);
}

// ---------- PROVEN: make_wp ----------
__global__ void make_wp(const float* __restrict__ Wq, const float* __restrict__ M,
                        unsigned short* __restrict__ WpT) {
    __shared__ float Mcol[64];
    int gid = blockIdx.x * 256 + threadIdx.x;  // b*65536 + d*1024 + h
    int h = gid & (H_ - 1);
    int d = (gid >> 10) & 63;
    int b = gid >> 16;
    if (threadIdx.x < 64) Mcol[threadIdx.x] = M[b * 4096 + threadIdx.x * 64 + d];
    __syncthreads();
    const float4* wq = (const float4*)(Wq + h * 64);
    float acc = 0.f;
#pragma unroll
    for (int e4 = 0; e4 < 16; ++e4) {
        float4 w = wq[e4];
        acc += w.x * Mcol[e4 * 4] + w.y * Mcol[e4 * 4 + 1] +
               w.z * Mcol[e4 * 4 + 2] + w.w * Mcol[e4 * 4 + 3];
    }
    WpT[gid] = f2bf(acc * 0.125f);
}

// ---------- final_proj4: round-1 proven structure + per-iter barrier for L1 dedup ----------
__global__ __launch_bounds__(256)
void final_proj4(const float* __restrict__ x, const unsigned short* __restrict__ WpT,
                 float* __restrict__ out) {
    int b = blockIdx.x / NCHUNK;
    int c = blockIdx.x % NCHUNK;
    int s0 = c * CHUNK;
    int wv = threadIdx.x >> 6, lane = threadIdx.x & 63;
    int r = lane & 15, kg = lane >> 4;
    const unsigned short* Wp = WpT + (size_t)b * (D_ * H_);

    f32x4 acc[4] = {};
    const float* xrow = x + ((size_t)b * S_ + s0 + wv * 16 + r) * H_;
    for (int h0 = 0; h0 < H_; h0 += 32) {
        __syncthreads();  // all 4 waves read the same Wp bytes this iter -> L1 hits
        int kb = h0 + kg * 8;
        float4 a0 = *(const float4*)(xrow + kb);
        float4 a1 = *(const float4*)(xrow + kb + 4);
        bf16x8 af = cvt8(a0, a1);
#pragma unroll
        for (int nt = 0; nt < 4; ++nt) {
            bf16x8 bw = *(const bf16x8*)(Wp + (nt * 16 + r) * H_ + kb);
            acc[nt] = __builtin_amdgcn_mfma_f32_16x16x32_bf16(af, bw, acc[nt], 0, 0, 0);
        }
    }
    float* orow = out + ((size_t)b * S_ + s0 + wv * 16) * 64;
#pragma unroll
    for (int nt = 0; nt < 4; ++nt)
#pragma unroll
        for (int i = 0; i < 4; ++i)
            orow[(kg * 4 + i) * 64 + nt * 16 + r] = acc[nt][i];
}

extern "C" void kernel_launch(void* const* d_in, const int* in_sizes, int n_in,
                              void* d_out, int out_size, void* d_ws, size_t ws_size,
                              hipStream_t stream) {
    const float* x  = (const float*)d_in[0];
    const float* Wk = (const float*)d_in[1];
    const float* Wq = (const float*)d_in[2];
    const float* Wv = (const float*)d_in[3];
    float* out = (float*)d_out;

    if (ws_size < 2949120) return;  // diagnostic guard (poison signature if ws too small)

    char* ws = (char*)d_ws;
    // layout (total 2,949,120 B):
    // WkT[128K] | WvT[128K] | WpT[512K] | M[64K fp32] | pMb[2M bf16]
    unsigned short* WkT = (unsigned short*)(ws);
    unsigned short* WvT = (unsigned short*)(ws + 131072);
    unsigned short* WpT = (unsigned short*)(ws + 262144);
    float* M            = (float*)(ws + 786432);
    unsigned short* pMb = (unsigned short*)(ws + 851968);

    prep_w<<<256, 256, 0, stream>>>(Wk, Wv, WkT, WvT);
    kv_moment6<<<256, 1024, 0, stream>>>(x, WkT, WvT, pMb);
    reduce_m6<<<64, 256, 0, stream>>>(pMb, M);
    make_wp<<<1024, 256, 0, stream>>>(Wq, M, WpT);
    final_proj4<<<256, 256, 0, stream>>>(x, WpT, out);
}

// Round 6
// 74.389 us; speedup vs baseline: 1.2595x; 1.2595x over previous
//
#include <hip/hip_runtime.h>
#include <hip/hip_bf16.h>

// Problem constants
#define B_ 4
#define S_ 4096
#define H_ 1024
#define D_ 64
#define CHUNK 64
#define NCHUNK (S_ / CHUNK)
#define BK 128          // h per K-step
#define KSTEPS (H_ / BK)

typedef short bf16x8 __attribute__((ext_vector_type(8)));
typedef short bf16x4 __attribute__((ext_vector_type(4)));
typedef float f32x4 __attribute__((ext_vector_type(4)));

__device__ inline unsigned short f2bf(float f) {
    union { float f; unsigned u; } v; v.f = f;
    return (unsigned short)((v.u + 0x7fffu + ((v.u >> 16) & 1u)) >> 16);
}
__device__ inline float bf2f(unsigned short u) {
    union { unsigned u; float f; } v; v.u = (unsigned)u << 16;
    return v.f;
}
__device__ inline bf16x8 cvt8(const float4& a, const float4& b) {
    bf16x8 r;
    r[0] = (short)f2bf(a.x); r[1] = (short)f2bf(a.y);
    r[2] = (short)f2bf(a.z); r[3] = (short)f2bf(a.w);
    r[4] = (short)f2bf(b.x); r[5] = (short)f2bf(b.y);
    r[6] = (short)f2bf(b.z); r[7] = (short)f2bf(b.w);
    return r;
}

// ---------- PROVEN: prep_w ----------
__global__ void prep_w(const float* __restrict__ Wk, const float* __restrict__ Wv,
                       unsigned short* __restrict__ WkT, unsigned short* __restrict__ WvT) {
    int gid = blockIdx.x * 256 + threadIdx.x;  // gid = d*H + h
    int d = gid >> 10;
    int h = gid & (H_ - 1);
    WkT[gid] = f2bf(Wk[h * D_ + d]);
    WvT[gid] = f2bf(Wv[h * D_ + d]);
}

// ---------- kv_moment7: LDS-staged weights, 64 rows/block, K-loop ----------
// Swizzle: tile [row=d 0..63][16 slots of 16B per BK=128 h]; store/read at
// slot_f = slot ^ ((row&7)<<1). Bijective per row; spreads the 16-r column
// read across 8 bank-groups (2-way = free per G4).
__global__ __launch_bounds__(256)
void kv_moment7(const float* __restrict__ x, const unsigned short* __restrict__ WkT,
                const unsigned short* __restrict__ WvT, unsigned short* __restrict__ pMb) {
    int blk = blockIdx.x;            // 0..255, 64 blocks per batch
    int b = blk >> 6;
    int s0 = (blk & 63) * 64;
    int tid = threadIdx.x;
    int wv = tid >> 6, lane = tid & 63;
    int r = lane & 15, kg = lane >> 4;

    __shared__ __align__(16) unsigned short WkL[8192];   // 16 KB swizzled [64][128]
    __shared__ __align__(16) unsigned short WvL[8192];   // 16 KB
    __shared__ __align__(16) unsigned short Klds[64][64];// 8 KB (round-1 proven stage-2)
    __shared__ __align__(16) unsigned short Vlds[64][64];// 8 KB  -> 48 KB total

    int st_row = tid >> 4;   // 0..15 (+ j*16)
    int st_s = tid & 15;

    f32x4 accK[4] = {}, accV[4] = {};
    const float* xrow = x + ((size_t)b * S_ + s0 + wv * 16 + r) * H_;

    for (int ks = 0; ks < KSTEPS; ++ks) {
        __syncthreads();  // previous step's LDS reads done before overwrite
#pragma unroll
        for (int j = 0; j < 4; ++j) {
            int row = j * 16 + st_row;
            int sf = st_s ^ ((row & 7) << 1);
            bf16x8 wk8 = *(const bf16x8*)(WkT + row * H_ + ks * BK + st_s * 8);
            bf16x8 wv8 = *(const bf16x8*)(WvT + row * H_ + ks * BK + st_s * 8);
            *(bf16x8*)&WkL[row * 128 + sf * 8] = wk8;
            *(bf16x8*)&WvL[row * 128 + sf * 8] = wv8;
        }
        __syncthreads();
#pragma unroll
        for (int kc = 0; kc < 4; ++kc) {
            int kb = ks * BK + kc * 32 + kg * 8;
            float4 a0 = *(const float4*)(xrow + kb);
            float4 a1 = *(const float4*)(xrow + kb + 4);
            bf16x8 af = cvt8(a0, a1);
            int slot = kc * 4 + kg;
#pragma unroll
            for (int nt = 0; nt < 4; ++nt) {
                int row = nt * 16 + r;                    // row&7 == r&7
                int sf = slot ^ ((r & 7) << 1);
                bf16x8 bk = *(const bf16x8*)&WkL[row * 128 + sf * 8];
                bf16x8 bv = *(const bf16x8*)&WvL[row * 128 + sf * 8];
                accK[nt] = __builtin_amdgcn_mfma_f32_16x16x32_bf16(af, bk, accK[nt], 0, 0, 0);
                accV[nt] = __builtin_amdgcn_mfma_f32_16x16x32_bf16(af, bv, accV[nt], 0, 0, 0);
            }
        }
    }

    // K,V -> LDS bf16 (round-1 proven D-layout mapping)
    __syncthreads();
#pragma unroll
    for (int nt = 0; nt < 4; ++nt)
#pragma unroll
        for (int i = 0; i < 4; ++i) {
            Klds[wv * 16 + kg * 4 + i][nt * 16 + r] = f2bf(accK[nt][i]);
            Vlds[wv * 16 + kg * 4 + i][nt * 16 + r] = f2bf(accV[nt][i]);
        }
    __syncthreads();

    // Stage 2 (round-1 proven): Mpart[e][d] = sum_{s<64} K[s][e]*V[s][d]
    f32x4 accM[4] = {};
#pragma unroll
    for (int ks2 = 0; ks2 < 2; ++ks2) {
        bf16x8 afm;
#pragma unroll
        for (int i = 0; i < 8; ++i)
            afm[i] = (short)Klds[ks2 * 32 + kg * 8 + i][wv * 16 + r];
#pragma unroll
        for (int nt = 0; nt < 4; ++nt) {
            bf16x8 bfv;
#pragma unroll
            for (int i = 0; i < 8; ++i)
                bfv[i] = (short)Vlds[ks2 * 32 + kg * 8 + i][nt * 16 + r];
            accM[nt] = __builtin_amdgcn_mfma_f32_16x16x32_bf16(afm, bfv, accM[nt], 0, 0, 0);
        }
    }
    unsigned short* outp = pMb + (size_t)blk * 4096;
#pragma unroll
    for (int nt = 0; nt < 4; ++nt)
#pragma unroll
        for (int i = 0; i < 4; ++i)
            outp[(wv * 16 + kg * 4 + i) * 64 + nt * 16 + r] = f2bf(accM[nt][i]);
}

// ---------- PROVEN: reduce_m6 (64 bf16 partials per batch) ----------
__global__ void reduce_m6(const unsigned short* __restrict__ pMb, float* __restrict__ M) {
    int gid = blockIdx.x * 256 + threadIdx.x;  // 0..16383
    int b = gid >> 12;
    int idx = gid & 4095;
    const unsigned short* p = pMb + (size_t)b * 64 * 4096 + idx;
    float a0 = 0.f, a1 = 0.f, a2 = 0.f, a3 = 0.f;
#pragma unroll 2
    for (int c = 0; c < 64; c += 4) {
        a0 += bf2f(p[(size_t)(c + 0) * 4096]);
        a1 += bf2f(p[(size_t)(c + 1) * 4096]);
        a2 += bf2f(p[(size_t)(c + 2) * 4096]);
        a3 += bf2f(p[(size_t)(c + 3) * 4096]);
    }
    M[gid] = (a0 + a1) + (a2 + a3);
}

// ---------- PROVEN: make_wp ----------
__global__ void make_wp(const float* __restrict__ Wq, const float* __restrict__ M,
                        unsigned short* __restrict__ WpT) {
    __shared__ float Mcol[64];
    int gid = blockIdx.x * 256 + threadIdx.x;  // b*65536 + d*1024 + h
    int h = gid & (H_ - 1);
    int d = (gid >> 10) & 63;
    int b = gid >> 16;
    if (threadIdx.x < 64) Mcol[threadIdx.x] = M[b * 4096 + threadIdx.x * 64 + d];
    __syncthreads();
    const float4* wq = (const float4*)(Wq + h * 64);
    float acc = 0.f;
#pragma unroll
    for (int e4 = 0; e4 < 16; ++e4) {
        float4 w = wq[e4];
        acc += w.x * Mcol[e4 * 4] + w.y * Mcol[e4 * 4 + 1] +
               w.z * Mcol[e4 * 4 + 2] + w.w * Mcol[e4 * 4 + 3];
    }
    WpT[gid] = f2bf(acc * 0.125f);
}

// ---------- final_proj5: LDS-staged Wp, same structure as kv_moment7 ----------
__global__ __launch_bounds__(256)
void final_proj5(const float* __restrict__ x, const unsigned short* __restrict__ WpT,
                 float* __restrict__ out) {
    int blk = blockIdx.x;            // 0..255
    int b = blk >> 6;
    int s0 = (blk & 63) * 64;
    int tid = threadIdx.x;
    int wv = tid >> 6, lane = tid & 63;
    int r = lane & 15, kg = lane >> 4;
    const unsigned short* Wp = WpT + (size_t)b * (D_ * H_);

    __shared__ __align__(16) unsigned short WpL[8192];  // 16 KB swizzled

    int st_row = tid >> 4;
    int st_s = tid & 15;

    f32x4 acc[4] = {};
    const float* xrow = x + ((size_t)b * S_ + s0 + wv * 16 + r) * H_;

    for (int ks = 0; ks < KSTEPS; ++ks) {
        __syncthreads();
#pragma unroll
        for (int j = 0; j < 4; ++j) {
            int row = j * 16 + st_row;
            int sf = st_s ^ ((row & 7) << 1);
            bf16x8 w8 = *(const bf16x8*)(Wp + row * H_ + ks * BK + st_s * 8);
            *(bf16x8*)&WpL[row * 128 + sf * 8] = w8;
        }
        __syncthreads();
#pragma unroll
        for (int kc = 0; kc < 4; ++kc) {
            int kb = ks * BK + kc * 32 + kg * 8;
            float4 a0 = *(const float4*)(xrow + kb);
            float4 a1 = *(const float4*)(xrow + kb + 4);
            bf16x8 af = cvt8(a0, a1);
            int slot = kc * 4 + kg;
#pragma unroll
            for (int nt = 0; nt < 4; ++nt) {
                int row = nt * 16 + r;
                int sf = slot ^ ((r & 7) << 1);
                bf16x8 bw = *(const bf16x8*)&WpL[row * 128 + sf * 8];
                acc[nt] = __builtin_amdgcn_mfma_f32_16x16x32_bf16(af, bw, acc[nt], 0, 0, 0);
            }
        }
    }
    float* orow = out + ((size_t)b * S_ + s0 + wv * 16) * 64;
#pragma unroll
    for (int nt = 0; nt < 4; ++nt)
#pragma unroll
        for (int i = 0; i < 4; ++i)
            orow[(kg * 4 + i) * 64 + nt * 16 + r] = acc[nt][i];
}

extern "C" void kernel_launch(void* const* d_in, const int* in_sizes, int n_in,
                              void* d_out, int out_size, void* d_ws, size_t ws_size,
                              hipStream_t stream) {
    const float* x  = (const float*)d_in[0];
    const float* Wk = (const float*)d_in[1];
    const float* Wq = (const float*)d_in[2];
    const float* Wv = (const float*)d_in[3];
    float* out = (float*)d_out;

    if (ws_size < 2949120) return;  // diagnostic guard

    char* ws = (char*)d_ws;
    // layout (total 2,949,120 B):
    // WkT[128K] | WvT[128K] | WpT[512K] | M[64K fp32] | pMb[2M bf16]
    unsigned short* WkT = (unsigned short*)(ws);
    unsigned short* WvT = (unsigned short*)(ws + 131072);
    unsigned short* WpT = (unsigned short*)(ws + 262144);
    float* M            = (float*)(ws + 786432);
    unsigned short* pMb = (unsigned short*)(ws + 851968);

    prep_w<<<256, 256, 0, stream>>>(Wk, Wv, WkT, WvT);
    kv_moment7<<<256, 256, 0, stream>>>(x, WkT, WvT, pMb);
    reduce_m6<<<64, 256, 0, stream>>>(pMb, M);
    make_wp<<<1024, 256, 0, stream>>>(Wq, M, WpT);
    final_proj5<<<256, 256, 0, stream>>>(x, WpT, out);
}

// Round 7
// 59.405 us; speedup vs baseline: 1.5772x; 1.2522x over previous
//
#include <hip/hip_runtime.h>
#include <hip/hip_bf16.h>

// Problem constants
#define B_ 4
#define S_ 4096
#define H_ 1024
#define D_ 64
#define BK 128
#define KSTEPS (H_ / BK)

typedef short bf16x8 __attribute__((ext_vector_type(8)));
typedef float f32x4 __attribute__((ext_vector_type(4)));

__device__ inline unsigned short f2bf(float f) {
    union { float f; unsigned u; } v; v.f = f;
    return (unsigned short)((v.u + 0x7fffu + ((v.u >> 16) & 1u)) >> 16);
}
__device__ inline float bf2f(unsigned short u) {
    union { unsigned u; float f; } v; v.u = (unsigned)u << 16;
    return v.f;
}
__device__ inline bf16x8 cvt8(const float4& a, const float4& b) {
    bf16x8 r;
    r[0] = (short)f2bf(a.x); r[1] = (short)f2bf(a.y);
    r[2] = (short)f2bf(a.z); r[3] = (short)f2bf(a.w);
    r[4] = (short)f2bf(b.x); r[5] = (short)f2bf(b.y);
    r[6] = (short)f2bf(b.z); r[7] = (short)f2bf(b.w);
    return r;
}

// ---------- PROVEN: prep_w ----------
__global__ void prep_w(const float* __restrict__ Wk, const float* __restrict__ Wv,
                       unsigned short* __restrict__ WkT, unsigned short* __restrict__ WvT) {
    int gid = blockIdx.x * 256 + threadIdx.x;  // gid = d*H + h
    int d = gid >> 10;
    int h = gid & (H_ - 1);
    WkT[gid] = f2bf(Wk[h * D_ + d]);
    WvT[gid] = f2bf(Wv[h * D_ + d]);
}

// ---------- kv_moment8: LDS-staged x (contiguous loads) + weights, pipelined ----------
__global__ __launch_bounds__(256)
void kv_moment8(const float* __restrict__ x, const unsigned short* __restrict__ WkT,
                const unsigned short* __restrict__ WvT, unsigned short* __restrict__ pMb) {
    int blk = blockIdx.x;            // 0..255, 64 blocks per batch
    int b = blk >> 6;
    int s0 = (blk & 63) * 64;
    int tid = threadIdx.x;
    int wv = tid >> 6, lane = tid & 63;
    int r = lane & 15, kg = lane >> 4;

    // xKV: x-tile during K-loop (swizzled bf16 [64 rows][128 cols]); reused as
    // Klds|Vlds ([64][64] each) for stage 2 after a barrier.
    __shared__ __align__(16) unsigned short xKV[8192];   // 16 KB
    __shared__ __align__(16) unsigned short WkL[8192];   // 16 KB (round-6 proven layout)
    __shared__ __align__(16) unsigned short WvL[8192];   // 16 KB  -> 48 KB total

    int strow = tid >> 4;    // 0..15
    int sts   = tid & 15;    // slot 0..15

    // staging registers
    float4 xr[8];
    bf16x8 wkr[4], wvr[4];

    const float* xbase = x + ((size_t)b * S_ + s0) * H_;

#define LOADX(KS)                                                              \
    _Pragma("unroll")                                                          \
    for (int p = 0; p < 4; ++p) {                                              \
        int row = p * 16 + strow;                                              \
        const float* src = xbase + (size_t)row * H_ + (KS) * BK + sts * 8;     \
        xr[2 * p]     = *(const float4*)(src);                                 \
        xr[2 * p + 1] = *(const float4*)(src + 4);                             \
    }
#define LOADW(KS)                                                              \
    _Pragma("unroll")                                                          \
    for (int j = 0; j < 4; ++j) {                                              \
        int row = j * 16 + strow;                                              \
        wkr[j] = *(const bf16x8*)(WkT + row * H_ + (KS) * BK + sts * 8);       \
        wvr[j] = *(const bf16x8*)(WvT + row * H_ + (KS) * BK + sts * 8);       \
    }

    LOADX(0);
    LOADW(0);

    f32x4 accK[4] = {}, accV[4] = {};

    for (int ks = 0; ks < KSTEPS; ++ks) {
        __syncthreads();  // prior compute done reading LDS
        // write staged regs -> LDS
#pragma unroll
        for (int p = 0; p < 4; ++p) {
            int row = p * 16 + strow;
            int sfx = sts ^ (row & 7);
            *(bf16x8*)&xKV[row * 128 + sfx * 8] = cvt8(xr[2 * p], xr[2 * p + 1]);
            int sfw = sts ^ ((row & 7) << 1);
            *(bf16x8*)&WkL[row * 128 + sfw * 8] = wkr[p];
            *(bf16x8*)&WvL[row * 128 + sfw * 8] = wvr[p];
        }
        __syncthreads();
        if (ks < KSTEPS - 1) {  // issue next step's loads; latency hides under MFMAs
            LOADX(ks + 1);
            LOADW(ks + 1);
        }
#pragma unroll
        for (int kc = 0; kc < 4; ++kc) {
            int slot = kc * 4 + kg;
            int arow = wv * 16 + r;                     // arow&7 == r&7
            bf16x8 af = *(const bf16x8*)&xKV[arow * 128 + (slot ^ (r & 7)) * 8];
#pragma unroll
            for (int nt = 0; nt < 4; ++nt) {
                int row = nt * 16 + r;
                int sfw = slot ^ ((row & 7) << 1);
                bf16x8 bk = *(const bf16x8*)&WkL[row * 128 + sfw * 8];
                bf16x8 bv = *(const bf16x8*)&WvL[row * 128 + sfw * 8];
                accK[nt] = __builtin_amdgcn_mfma_f32_16x16x32_bf16(af, bk, accK[nt], 0, 0, 0);
                accV[nt] = __builtin_amdgcn_mfma_f32_16x16x32_bf16(af, bv, accV[nt], 0, 0, 0);
            }
        }
    }

    // K,V -> LDS bf16 (round-1 proven D-layout mapping); xKV reused as Klds|Vlds
    __syncthreads();
#pragma unroll
    for (int nt = 0; nt < 4; ++nt)
#pragma unroll
        for (int i = 0; i < 4; ++i) {
            int srow = wv * 16 + kg * 4 + i, col = nt * 16 + r;
            xKV[srow * 64 + col]        = f2bf(accK[nt][i]);   // Klds
            xKV[4096 + srow * 64 + col] = f2bf(accV[nt][i]);   // Vlds
        }
    __syncthreads();

    // Stage 2 (round-1 proven): Mpart[e][d] = sum_{s<64} K[s][e]*V[s][d]
    f32x4 accM[4] = {};
#pragma unroll
    for (int ks2 = 0; ks2 < 2; ++ks2) {
        bf16x8 afm;
#pragma unroll
        for (int i = 0; i < 8; ++i)
            afm[i] = (short)xKV[(ks2 * 32 + kg * 8 + i) * 64 + wv * 16 + r];
#pragma unroll
        for (int nt = 0; nt < 4; ++nt) {
            bf16x8 bfv;
#pragma unroll
            for (int i = 0; i < 8; ++i)
                bfv[i] = (short)xKV[4096 + (ks2 * 32 + kg * 8 + i) * 64 + nt * 16 + r];
            accM[nt] = __builtin_amdgcn_mfma_f32_16x16x32_bf16(afm, bfv, accM[nt], 0, 0, 0);
        }
    }
    unsigned short* outp = pMb + (size_t)blk * 4096;
#pragma unroll
    for (int nt = 0; nt < 4; ++nt)
#pragma unroll
        for (int i = 0; i < 4; ++i)
            outp[(wv * 16 + kg * 4 + i) * 64 + nt * 16 + r] = f2bf(accM[nt][i]);
#undef LOADX
#undef LOADW
}

// ---------- PROVEN: reduce_m6 (64 bf16 partials per batch) ----------
__global__ void reduce_m6(const unsigned short* __restrict__ pMb, float* __restrict__ M) {
    int gid = blockIdx.x * 256 + threadIdx.x;  // 0..16383
    int b = gid >> 12;
    int idx = gid & 4095;
    const unsigned short* p = pMb + (size_t)b * 64 * 4096 + idx;
    float a0 = 0.f, a1 = 0.f, a2 = 0.f, a3 = 0.f;
#pragma unroll 2
    for (int c = 0; c < 64; c += 4) {
        a0 += bf2f(p[(size_t)(c + 0) * 4096]);
        a1 += bf2f(p[(size_t)(c + 1) * 4096]);
        a2 += bf2f(p[(size_t)(c + 2) * 4096]);
        a3 += bf2f(p[(size_t)(c + 3) * 4096]);
    }
    M[gid] = (a0 + a1) + (a2 + a3);
}

// ---------- PROVEN: make_wp ----------
__global__ void make_wp(const float* __restrict__ Wq, const float* __restrict__ M,
                        unsigned short* __restrict__ WpT) {
    __shared__ float Mcol[64];
    int gid = blockIdx.x * 256 + threadIdx.x;  // b*65536 + d*1024 + h
    int h = gid & (H_ - 1);
    int d = (gid >> 10) & 63;
    int b = gid >> 16;
    if (threadIdx.x < 64) Mcol[threadIdx.x] = M[b * 4096 + threadIdx.x * 64 + d];
    __syncthreads();
    const float4* wq = (const float4*)(Wq + h * 64);
    float acc = 0.f;
#pragma unroll
    for (int e4 = 0; e4 < 16; ++e4) {
        float4 w = wq[e4];
        acc += w.x * Mcol[e4 * 4] + w.y * Mcol[e4 * 4 + 1] +
               w.z * Mcol[e4 * 4 + 2] + w.w * Mcol[e4 * 4 + 3];
    }
    WpT[gid] = f2bf(acc * 0.125f);
}

// ---------- final_proj6: LDS-staged x + Wp, pipelined (same structure as kv) ----------
__global__ __launch_bounds__(256)
void final_proj6(const float* __restrict__ x, const unsigned short* __restrict__ WpT,
                 float* __restrict__ out) {
    int blk = blockIdx.x;            // 0..255
    int b = blk >> 6;
    int s0 = (blk & 63) * 64;
    int tid = threadIdx.x;
    int wv = tid >> 6, lane = tid & 63;
    int r = lane & 15, kg = lane >> 4;
    const unsigned short* Wp = WpT + (size_t)b * (D_ * H_);

    __shared__ __align__(16) unsigned short xL[8192];   // 16 KB
    __shared__ __align__(16) unsigned short WpL[8192];  // 16 KB

    int strow = tid >> 4, sts = tid & 15;

    float4 xr[8];
    bf16x8 wpr[4];
    const float* xbase = x + ((size_t)b * S_ + s0) * H_;

#define LOADX(KS)                                                              \
    _Pragma("unroll")                                                          \
    for (int p = 0; p < 4; ++p) {                                              \
        int row = p * 16 + strow;                                              \
        const float* src = xbase + (size_t)row * H_ + (KS) * BK + sts * 8;     \
        xr[2 * p]     = *(const float4*)(src);                                 \
        xr[2 * p + 1] = *(const float4*)(src + 4);                             \
    }
#define LOADW(KS)                                                              \
    _Pragma("unroll")                                                          \
    for (int j = 0; j < 4; ++j) {                                              \
        int row = j * 16 + strow;                                              \
        wpr[j] = *(const bf16x8*)(Wp + row * H_ + (KS) * BK + sts * 8);        \
    }

    LOADX(0);
    LOADW(0);

    f32x4 acc[4] = {};

    for (int ks = 0; ks < KSTEPS; ++ks) {
        __syncthreads();
#pragma unroll
        for (int p = 0; p < 4; ++p) {
            int row = p * 16 + strow;
            int sfx = sts ^ (row & 7);
            *(bf16x8*)&xL[row * 128 + sfx * 8] = cvt8(xr[2 * p], xr[2 * p + 1]);
            int sfw = sts ^ ((row & 7) << 1);
            *(bf16x8*)&WpL[row * 128 + sfw * 8] = wpr[p];
        }
        __syncthreads();
        if (ks < KSTEPS - 1) {
            LOADX(ks + 1);
            LOADW(ks + 1);
        }
#pragma unroll
        for (int kc = 0; kc < 4; ++kc) {
            int slot = kc * 4 + kg;
            int arow = wv * 16 + r;
            bf16x8 af = *(const bf16x8*)&xL[arow * 128 + (slot ^ (r & 7)) * 8];
#pragma unroll
            for (int nt = 0; nt < 4; ++nt) {
                int row = nt * 16 + r;
                int sfw = slot ^ ((row & 7) << 1);
                bf16x8 bw = *(const bf16x8*)&WpL[row * 128 + sfw * 8];
                acc[nt] = __builtin_amdgcn_mfma_f32_16x16x32_bf16(af, bw, acc[nt], 0, 0, 0);
            }
        }
    }
    float* orow = out + ((size_t)b * S_ + s0 + wv * 16) * 64;
#pragma unroll
    for (int nt = 0; nt < 4; ++nt)
#pragma unroll
        for (int i = 0; i < 4; ++i)
            orow[(kg * 4 + i) * 64 + nt * 16 + r] = acc[nt][i];
#undef LOADX
#undef LOADW
}

extern "C" void kernel_launch(void* const* d_in, const int* in_sizes, int n_in,
                              void* d_out, int out_size, void* d_ws, size_t ws_size,
                              hipStream_t stream) {
    const float* x  = (const float*)d_in[0];
    const float* Wk = (const float*)d_in[1];
    const float* Wq = (const float*)d_in[2];
    const float* Wv = (const float*)d_in[3];
    float* out = (float*)d_out;

    if (ws_size < 2949120) return;  // diagnostic guard

    char* ws = (char*)d_ws;
    // layout (total 2,949,120 B):
    // WkT[128K] | WvT[128K] | WpT[512K] | M[64K fp32] | pMb[2M bf16]
    unsigned short* WkT = (unsigned short*)(ws);
    unsigned short* WvT = (unsigned short*)(ws + 131072);
    unsigned short* WpT = (unsigned short*)(ws + 262144);
    float* M            = (float*)(ws + 786432);
    unsigned short* pMb = (unsigned short*)(ws + 851968);

    prep_w<<<256, 256, 0, stream>>>(Wk, Wv, WkT, WvT);
    kv_moment8<<<256, 256, 0, stream>>>(x, WkT, WvT, pMb);
    reduce_m6<<<64, 256, 0, stream>>>(pMb, M);
    make_wp<<<1024, 256, 0, stream>>>(Wq, M, WpT);
    final_proj6<<<256, 256, 0, stream>>>(x, WpT, out);
}

// Round 8
// 57.687 us; speedup vs baseline: 1.6241x; 1.0298x over previous
//
#include <hip/hip_runtime.h>
#include <hip/hip_bf16.h>

// Problem constants
#define B_ 4
#define S_ 4096
#define H_ 1024
#define D_ 64
#define BK 64
#define KSTEPS (H_ / BK)   // 16

typedef short bf16x8 __attribute__((ext_vector_type(8)));
typedef float f32x4 __attribute__((ext_vector_type(4)));

__device__ inline unsigned short f2bf(float f) {
    union { float f; unsigned u; } v; v.f = f;
    return (unsigned short)((v.u + 0x7fffu + ((v.u >> 16) & 1u)) >> 16);
}
__device__ inline float bf2f(unsigned short u) {
    union { unsigned u; float f; } v; v.u = (unsigned)u << 16;
    return v.f;
}
__device__ inline bf16x8 cvt8(const float4& a, const float4& b) {
    bf16x8 r;
    r[0] = (short)f2bf(a.x); r[1] = (short)f2bf(a.y);
    r[2] = (short)f2bf(a.z); r[3] = (short)f2bf(a.w);
    r[4] = (short)f2bf(b.x); r[5] = (short)f2bf(b.y);
    r[6] = (short)f2bf(b.z); r[7] = (short)f2bf(b.w);
    return r;
}

// ---------- PROVEN: prep_w ----------
__global__ void prep_w(const float* __restrict__ Wk, const float* __restrict__ Wv,
                       unsigned short* __restrict__ WkT, unsigned short* __restrict__ WvT) {
    int gid = blockIdx.x * 256 + threadIdx.x;  // gid = d*H + h
    int d = gid >> 10;
    int h = gid & (H_ - 1);
    WkT[gid] = f2bf(Wk[h * D_ + d]);
    WvT[gid] = f2bf(Wv[h * D_ + d]);
}

// ---------- kv_moment9: dbuf LDS, 8 waves (4 s-subtiles x {K,V}), BK=64 ----------
// LDS map (ushort idx): xL buf = L[buf*4096], WkL = L[8192+buf*4096],
// WvL = L[16384+buf*4096]. After K-loop: Klds = L[0..4095], Vlds = L[4096..8191].
// Tiles are [64 rows][8 slots of 8 bf16]; slot swizzle sf = slot ^ (row&7).
__global__ __launch_bounds__(512)
void kv_moment9(const float* __restrict__ x, const unsigned short* __restrict__ WkT,
                const unsigned short* __restrict__ WvT, unsigned short* __restrict__ pMb) {
    int blk = blockIdx.x;            // 0..255
    int b = blk >> 6;
    int c = blk & 63;
    int s0 = c * 64;
    int tid = threadIdx.x;
    int w = tid >> 6, lane = tid & 63;
    int r = lane & 15, kg = lane >> 4;
    int sv = w & 3, kvsel = w >> 2;  // s-subtile, 0=K 1=V

    __shared__ __align__(16) unsigned short L[24576];  // 48 KB

    int strow = tid >> 3, sts = tid & 7;
    int sf_st = sts ^ (strow & 7);
    const float* xbase = x + ((size_t)b * S_ + s0) * H_;

    float4 xr0, xr1;
    bf16x8 wk8, wv8;

#define LOADX(KS) do {                                                        \
        const float* src = xbase + (size_t)strow * H_ + (KS) * BK + sts * 8;  \
        xr0 = *(const float4*)(src);                                          \
        xr1 = *(const float4*)(src + 4);                                      \
    } while (0)
#define LOADW(KS) do {                                                        \
        wk8 = *(const bf16x8*)(WkT + strow * H_ + (KS) * BK + sts * 8);       \
        wv8 = *(const bf16x8*)(WvT + strow * H_ + (KS) * BK + sts * 8);       \
    } while (0)
#define WRITE(BUF) do {                                                       \
        int o = strow * 64 + sf_st * 8;                                       \
        *(bf16x8*)&L[(BUF) * 4096 + o]        = cvt8(xr0, xr1);               \
        *(bf16x8*)&L[8192 + (BUF) * 4096 + o] = wk8;                          \
        *(bf16x8*)&L[16384 + (BUF) * 4096 + o] = wv8;                         \
    } while (0)

    LOADX(0); LOADW(0);
    WRITE(0);
    LOADX(1); LOADW(1);
    __syncthreads();

    f32x4 acc[4] = {};
    int arow_off = (sv * 16 + r) * 64;
    int wbase = 8192 + kvsel * 8192;

    for (int ks = 0; ks < KSTEPS; ++ks) {
        int cur = ks & 1;
        if (ks < KSTEPS - 1) WRITE(cur ^ 1);
        if (ks < KSTEPS - 2) { LOADX(ks + 2); LOADW(ks + 2); }
#pragma unroll
        for (int kc = 0; kc < 2; ++kc) {
            int slot = kc * 4 + kg;
            int sf = (slot ^ (r & 7)) * 8;
            bf16x8 af = *(const bf16x8*)&L[cur * 4096 + arow_off + sf];
#pragma unroll
            for (int nt = 0; nt < 4; ++nt) {
                bf16x8 bw = *(const bf16x8*)&L[wbase + cur * 4096 + (nt * 16 + r) * 64 + sf];
                acc[nt] = __builtin_amdgcn_mfma_f32_16x16x32_bf16(af, bw, acc[nt], 0, 0, 0);
            }
        }
        __syncthreads();
    }

    // K/V -> LDS bf16 (round-1 proven D-layout: row = sv*16+kg*4+i, col = nt*16+r)
#pragma unroll
    for (int nt = 0; nt < 4; ++nt)
#pragma unroll
        for (int i = 0; i < 4; ++i)
            L[kvsel * 4096 + (sv * 16 + kg * 4 + i) * 64 + nt * 16 + r] = f2bf(acc[nt][i]);
    __syncthreads();

    // Stage 2 (round-1 proven math): Mpart[e][d] = sum_{s<64} K[s][e]*V[s][d]
    int et = w & 3, dh2 = w >> 2;
    f32x4 accM[2] = {};
#pragma unroll
    for (int ks2 = 0; ks2 < 2; ++ks2) {
        bf16x8 afm;
#pragma unroll
        for (int i = 0; i < 8; ++i)
            afm[i] = (short)L[(ks2 * 32 + kg * 8 + i) * 64 + et * 16 + r];
#pragma unroll
        for (int t = 0; t < 2; ++t) {
            int nt = dh2 * 2 + t;
            bf16x8 bfv;
#pragma unroll
            for (int i = 0; i < 8; ++i)
                bfv[i] = (short)L[4096 + (ks2 * 32 + kg * 8 + i) * 64 + nt * 16 + r];
            accM[t] = __builtin_amdgcn_mfma_f32_16x16x32_bf16(afm, bfv, accM[t], 0, 0, 0);
        }
    }
    // pMb layout: [b][idx][chunk]  (chunk-contiguous for coalesced reduce)
#pragma unroll
    for (int t = 0; t < 2; ++t)
#pragma unroll
        for (int i = 0; i < 4; ++i) {
            int idx = (et * 16 + kg * 4 + i) * 64 + (dh2 * 2 + t) * 16 + r;
            pMb[((size_t)b * 4096 + idx) * 64 + c] = f2bf(accM[t][i]);
        }
#undef LOADX
#undef LOADW
#undef WRITE
}

// ---------- reduce_m7: contiguous 64-chunk read per output ----------
__global__ void reduce_m7(const unsigned short* __restrict__ pMb, float* __restrict__ M) {
    int gid = blockIdx.x * 256 + threadIdx.x;  // 0..16383 = b*4096 + idx
    const unsigned short* p = pMb + (size_t)gid * 64;
    float s = 0.f;
#pragma unroll
    for (int j = 0; j < 8; ++j) {
        bf16x8 v = *(const bf16x8*)(p + j * 8);
#pragma unroll
        for (int e = 0; e < 8; ++e) s += bf2f((unsigned short)v[e]);
    }
    M[gid] = s;
}

// ---------- PROVEN: make_wp ----------
__global__ void make_wp(const float* __restrict__ Wq, const float* __restrict__ M,
                        unsigned short* __restrict__ WpT) {
    __shared__ float Mcol[64];
    int gid = blockIdx.x * 256 + threadIdx.x;  // b*65536 + d*1024 + h
    int h = gid & (H_ - 1);
    int d = (gid >> 10) & 63;
    int b = gid >> 16;
    if (threadIdx.x < 64) Mcol[threadIdx.x] = M[b * 4096 + threadIdx.x * 64 + d];
    __syncthreads();
    const float4* wq = (const float4*)(Wq + h * 64);
    float acc = 0.f;
#pragma unroll
    for (int e4 = 0; e4 < 16; ++e4) {
        float4 w = wq[e4];
        acc += w.x * Mcol[e4 * 4] + w.y * Mcol[e4 * 4 + 1] +
               w.z * Mcol[e4 * 4 + 2] + w.w * Mcol[e4 * 4 + 3];
    }
    WpT[gid] = f2bf(acc * 0.125f);
}

// ---------- final_proj7: dbuf LDS, 8 waves (4 s-subtiles x 2 col-halves) ----------
__global__ __launch_bounds__(512)
void final_proj7(const float* __restrict__ x, const unsigned short* __restrict__ WpT,
                 float* __restrict__ out) {
    int blk = blockIdx.x;            // 0..255
    int b = blk >> 6;
    int s0 = (blk & 63) * 64;
    int tid = threadIdx.x;
    int w = tid >> 6, lane = tid & 63;
    int r = lane & 15, kg = lane >> 4;
    int sv = w & 3, nh = w >> 2;
    const unsigned short* Wp = WpT + (size_t)b * (D_ * H_);

    __shared__ __align__(16) unsigned short L[16384];  // 32 KB: xL[2] | WpL[2]

    int strow = tid >> 3, sts = tid & 7;
    int sf_st = sts ^ (strow & 7);
    const float* xbase = x + ((size_t)b * S_ + s0) * H_;

    float4 xr0, xr1;
    bf16x8 wp8;

#define LOADX(KS) do {                                                        \
        const float* src = xbase + (size_t)strow * H_ + (KS) * BK + sts * 8;  \
        xr0 = *(const float4*)(src);                                          \
        xr1 = *(const float4*)(src + 4);                                      \
    } while (0)
#define LOADW(KS) do {                                                        \
        wp8 = *(const bf16x8*)(Wp + strow * H_ + (KS) * BK + sts * 8);        \
    } while (0)
#define WRITE(BUF) do {                                                       \
        int o = strow * 64 + sf_st * 8;                                       \
        *(bf16x8*)&L[(BUF) * 4096 + o]        = cvt8(xr0, xr1);               \
        *(bf16x8*)&L[8192 + (BUF) * 4096 + o] = wp8;                          \
    } while (0)

    LOADX(0); LOADW(0);
    WRITE(0);
    LOADX(1); LOADW(1);
    __syncthreads();

    f32x4 acc[2] = {};
    int arow_off = (sv * 16 + r) * 64;

    for (int ks = 0; ks < KSTEPS; ++ks) {
        int cur = ks & 1;
        if (ks < KSTEPS - 1) WRITE(cur ^ 1);
        if (ks < KSTEPS - 2) { LOADX(ks + 2); LOADW(ks + 2); }
#pragma unroll
        for (int kc = 0; kc < 2; ++kc) {
            int slot = kc * 4 + kg;
            int sf = (slot ^ (r & 7)) * 8;
            bf16x8 af = *(const bf16x8*)&L[cur * 4096 + arow_off + sf];
#pragma unroll
            for (int t = 0; t < 2; ++t) {
                int nt = nh * 2 + t;
                bf16x8 bw = *(const bf16x8*)&L[8192 + cur * 4096 + (nt * 16 + r) * 64 + sf];
                acc[t] = __builtin_amdgcn_mfma_f32_16x16x32_bf16(af, bw, acc[t], 0, 0, 0);
            }
        }
        __syncthreads();
    }

    float* orow = out + ((size_t)b * S_ + s0 + sv * 16) * 64;
#pragma unroll
    for (int t = 0; t < 2; ++t)
#pragma unroll
        for (int i = 0; i < 4; ++i)
            orow[(kg * 4 + i) * 64 + (nh * 2 + t) * 16 + r] = acc[t][i];
#undef LOADX
#undef LOADW
#undef WRITE
}

extern "C" void kernel_launch(void* const* d_in, const int* in_sizes, int n_in,
                              void* d_out, int out_size, void* d_ws, size_t ws_size,
                              hipStream_t stream) {
    const float* x  = (const float*)d_in[0];
    const float* Wk = (const float*)d_in[1];
    const float* Wq = (const float*)d_in[2];
    const float* Wv = (const float*)d_in[3];
    float* out = (float*)d_out;

    if (ws_size < 2949120) return;  // diagnostic guard

    char* ws = (char*)d_ws;
    // layout (total 2,949,120 B):
    // WkT[128K] | WvT[128K] | WpT[512K] | M[64K fp32] | pMb[2M bf16]
    unsigned short* WkT = (unsigned short*)(ws);
    unsigned short* WvT = (unsigned short*)(ws + 131072);
    unsigned short* WpT = (unsigned short*)(ws + 262144);
    float* M            = (float*)(ws + 786432);
    unsigned short* pMb = (unsigned short*)(ws + 851968);

    prep_w<<<256, 256, 0, stream>>>(Wk, Wv, WkT, WvT);
    kv_moment9<<<256, 512, 0, stream>>>(x, WkT, WvT, pMb);
    reduce_m7<<<64, 256, 0, stream>>>(pMb, M);
    make_wp<<<1024, 256, 0, stream>>>(Wq, M, WpT);
    final_proj7<<<256, 512, 0, stream>>>(x, WpT, out);
}

// Round 9
// 37.528 us; speedup vs baseline: 2.4966x; 1.5372x over previous
//
#include <hip/hip_runtime.h>
#include <hip/hip_bf16.h>

// Problem constants
#define B_ 4
#define S_ 4096
#define H_ 1024
#define D_ 64
#define BK 64
#define KSTEPS (H_ / BK)   // 16

typedef short bf16x8 __attribute__((ext_vector_type(8)));
typedef float f32x4 __attribute__((ext_vector_type(4)));

__device__ inline unsigned short f2bf(float f) {
    union { float f; unsigned u; } v; v.f = f;
    return (unsigned short)((v.u + 0x7fffu + ((v.u >> 16) & 1u)) >> 16);
}
__device__ inline float bf2f(unsigned short u) {
    union { unsigned u; float f; } v; v.u = (unsigned)u << 16;
    return v.f;
}
__device__ inline bf16x8 cvt8(const float4& a, const float4& b) {
    bf16x8 r;
    r[0] = (short)f2bf(a.x); r[1] = (short)f2bf(a.y);
    r[2] = (short)f2bf(a.z); r[3] = (short)f2bf(a.w);
    r[4] = (short)f2bf(b.x); r[5] = (short)f2bf(b.y);
    r[6] = (short)f2bf(b.z); r[7] = (short)f2bf(b.w);
    return r;
}

// ---------- prep_w3: transpose Wk,Wv,Wq ([H][D] fp32) -> WT[pj][D][H] bf16 ----------
__global__ void prep_w3(const float* __restrict__ Wk, const float* __restrict__ Wv,
                        const float* __restrict__ Wq, unsigned short* __restrict__ WT) {
    int gid = blockIdx.x * 256 + threadIdx.x;  // gid = d*H + h
    int d = gid >> 10;
    int h = gid & (H_ - 1);
    WT[gid]           = f2bf(Wk[h * D_ + d]);
    WT[65536 + gid]   = f2bf(Wv[h * D_ + d]);
    WT[131072 + gid]  = f2bf(Wq[h * D_ + d]);
}

// ---------- kv_moment10: K,V,Q fused; dbuf LDS; 12 waves (4 sv x {K,V,Q}) ----------
// LDS (ushort idx): x bufs L[0..4095],[4096..8191]; W[pj][buf] at 8192+(pj*2+buf)*4096.
// Tiles [64 rows][8 slots x 8 bf16], slot swizzle sf = slot ^ (row&7)  (round-8 proven).
// After K-loop: Klds = L[0..4095], Vlds = L[4096..8191] (x bufs dead).
__global__ __launch_bounds__(768)
void kv_moment10(const float* __restrict__ x, const unsigned short* __restrict__ WT,
                 unsigned short* __restrict__ pMb, unsigned short* __restrict__ Qb) {
    int blk = blockIdx.x;            // 0..255
    int b = blk >> 6;
    int c = blk & 63;
    int s0 = c * 64;
    int tid = threadIdx.x;
    int w = tid >> 6, lane = tid & 63;
    int r = lane & 15, kg = lane >> 4;
    int sv = w & 3, pj = w >> 2;     // s-subtile 0..3; 0=K 1=V 2=Q

    __shared__ __align__(16) unsigned short L[32768];  // 64 KB

    // x staging map (threads 0..511, round-8 proven)
    int strow = tid >> 3, sts = tid & 7;
    int sf_st = sts ^ (strow & 7);
    // weight staging map: 1536 slots of 16B, 2 per thread
    int ws0 = tid * 2, ws1 = tid * 2 + 1;
    int wpj0 = ws0 >> 9, wpj1 = ws1 >> 9;
    int wp0 = ws0 & 511, wp1 = ws1 & 511;
    int wrow0 = wp0 >> 3, wst0 = wp0 & 7, wsf0 = wst0 ^ (wrow0 & 7);
    int wrow1 = wp1 >> 3, wst1 = wp1 & 7, wsf1 = wst1 ^ (wrow1 & 7);

    const float* xbase = x + ((size_t)b * S_ + s0) * H_;

    float4 xr0, xr1;
    bf16x8 wr0, wr1;

#define LOADX(KS) do { if (tid < 512) {                                       \
        const float* src = xbase + (size_t)strow * H_ + (KS) * BK + sts * 8;  \
        xr0 = *(const float4*)(src);                                          \
        xr1 = *(const float4*)(src + 4); } } while (0)
#define LOADW(KS) do {                                                        \
        wr0 = *(const bf16x8*)(WT + wpj0 * 65536 + wrow0 * H_ + (KS) * BK + wst0 * 8); \
        wr1 = *(const bf16x8*)(WT + wpj1 * 65536 + wrow1 * H_ + (KS) * BK + wst1 * 8); \
    } while (0)
#define WRITE(BUF) do {                                                       \
        if (tid < 512)                                                        \
            *(bf16x8*)&L[(BUF) * 4096 + strow * 64 + sf_st * 8] = cvt8(xr0, xr1); \
        *(bf16x8*)&L[8192 + (wpj0 * 2 + (BUF)) * 4096 + wrow0 * 64 + wsf0 * 8] = wr0; \
        *(bf16x8*)&L[8192 + (wpj1 * 2 + (BUF)) * 4096 + wrow1 * 64 + wsf1 * 8] = wr1; \
    } while (0)

    LOADX(0); LOADW(0);
    WRITE(0);
    LOADX(1); LOADW(1);
    __syncthreads();

    f32x4 acc[4] = {};
    int arow_off = (sv * 16 + r) * 64;

    for (int ks = 0; ks < KSTEPS; ++ks) {
        int cur = ks & 1;
        if (ks < KSTEPS - 1) WRITE(cur ^ 1);
        if (ks < KSTEPS - 2) { LOADX(ks + 2); LOADW(ks + 2); }
#pragma unroll
        for (int kc = 0; kc < 2; ++kc) {
            int slot = kc * 4 + kg;
            int sf = (slot ^ (r & 7)) * 8;
            bf16x8 af = *(const bf16x8*)&L[cur * 4096 + arow_off + sf];
#pragma unroll
            for (int nt = 0; nt < 4; ++nt) {
                bf16x8 bw = *(const bf16x8*)&L[8192 + (pj * 2 + cur) * 4096 + (nt * 16 + r) * 64 + sf];
                acc[nt] = __builtin_amdgcn_mfma_f32_16x16x32_bf16(af, bw, acc[nt], 0, 0, 0);
            }
        }
        __syncthreads();
    }

    // K,V -> LDS (round-8 proven D-layout); Q -> global Qb
    if (pj < 2) {
#pragma unroll
        for (int nt = 0; nt < 4; ++nt)
#pragma unroll
            for (int i = 0; i < 4; ++i)
                L[pj * 4096 + (sv * 16 + kg * 4 + i) * 64 + nt * 16 + r] = f2bf(acc[nt][i]);
    }
    __syncthreads();
    if (pj == 2) {
        unsigned short* qrow = Qb + ((size_t)b * S_ + s0 + sv * 16) * 64;
#pragma unroll
        for (int nt = 0; nt < 4; ++nt)
#pragma unroll
            for (int i = 0; i < 4; ++i)
                qrow[(kg * 4 + i) * 64 + nt * 16 + r] = f2bf(acc[nt][i]);
    } else if (w < 8) {
        // Stage 2 (round-8 proven): Mpart[e][d] = sum_{s<64} K[s][e]*V[s][d]
        int et = w & 3, dh2 = w >> 2;
        f32x4 accM[2] = {};
#pragma unroll
        for (int ks2 = 0; ks2 < 2; ++ks2) {
            bf16x8 afm;
#pragma unroll
            for (int i = 0; i < 8; ++i)
                afm[i] = (short)L[(ks2 * 32 + kg * 8 + i) * 64 + et * 16 + r];
#pragma unroll
            for (int t = 0; t < 2; ++t) {
                int nt = dh2 * 2 + t;
                bf16x8 bfv;
#pragma unroll
                for (int i = 0; i < 8; ++i)
                    bfv[i] = (short)L[4096 + (ks2 * 32 + kg * 8 + i) * 64 + nt * 16 + r];
                accM[t] = __builtin_amdgcn_mfma_f32_16x16x32_bf16(afm, bfv, accM[t], 0, 0, 0);
            }
        }
        // pMb layout [b][idx][chunk] (round-8 proven)
#pragma unroll
        for (int t = 0; t < 2; ++t)
#pragma unroll
            for (int i = 0; i < 4; ++i) {
                int idx = (et * 16 + kg * 4 + i) * 64 + (dh2 * 2 + t) * 16 + r;
                pMb[((size_t)b * 4096 + idx) * 64 + c] = f2bf(accM[t][i]);
            }
    }
#undef LOADX
#undef LOADW
#undef WRITE
}

// ---------- reduce_m8: contiguous 64-chunk read, folds 1/sqrt(D)=1/8 ----------
__global__ void reduce_m8(const unsigned short* __restrict__ pMb, float* __restrict__ M8) {
    int gid = blockIdx.x * 256 + threadIdx.x;  // 0..16383 = b*4096 + idx
    const unsigned short* p = pMb + (size_t)gid * 64;
    float s = 0.f;
#pragma unroll
    for (int j = 0; j < 8; ++j) {
        bf16x8 v = *(const bf16x8*)(p + j * 8);
#pragma unroll
        for (int e = 0; e < 8; ++e) s += bf2f((unsigned short)v[e]);
    }
    M8[gid] = s * 0.125f;
}

// ---------- final_qm: out[b][s][d] = sum_e Q[b][s][e] * M8[b][e][d] ----------
__global__ __launch_bounds__(256)
void final_qm(const unsigned short* __restrict__ Qb, const float* __restrict__ M8,
              float* __restrict__ out) {
    int blk = blockIdx.x;            // 0..255
    int b = blk >> 6;
    int s0 = (blk & 63) * 64;
    int tid = threadIdx.x;
    int wv = tid >> 6, lane = tid & 63;
    int r = lane & 15, kg = lane >> 4;

    __shared__ unsigned short Ml[4096];  // M8 as bf16 [e][d]
#pragma unroll
    for (int j = 0; j < 16; ++j) {
        int i2 = j * 256 + tid;
        Ml[i2] = f2bf(M8[b * 4096 + i2]);
    }
    __syncthreads();

    const unsigned short* qrow = Qb + ((size_t)b * S_ + s0 + wv * 16 + r) * 64;
    f32x4 acc[4] = {};
#pragma unroll
    for (int ks2 = 0; ks2 < 2; ++ks2) {
        bf16x8 af = *(const bf16x8*)(qrow + ks2 * 32 + kg * 8);
#pragma unroll
        for (int nt = 0; nt < 4; ++nt) {
            bf16x8 bfm;
#pragma unroll
            for (int i = 0; i < 8; ++i)
                bfm[i] = (short)Ml[(ks2 * 32 + kg * 8 + i) * 64 + nt * 16 + r];
            acc[nt] = __builtin_amdgcn_mfma_f32_16x16x32_bf16(af, bfm, acc[nt], 0, 0, 0);
        }
    }
    float* orow = out + ((size_t)b * S_ + s0 + wv * 16) * 64;
#pragma unroll
    for (int nt = 0; nt < 4; ++nt)
#pragma unroll
        for (int i = 0; i < 4; ++i)
            orow[(kg * 4 + i) * 64 + nt * 16 + r] = acc[nt][i];
}

extern "C" void kernel_launch(void* const* d_in, const int* in_sizes, int n_in,
                              void* d_out, int out_size, void* d_ws, size_t ws_size,
                              hipStream_t stream) {
    const float* x  = (const float*)d_in[0];
    const float* Wk = (const float*)d_in[1];
    const float* Wq = (const float*)d_in[2];
    const float* Wv = (const float*)d_in[3];
    float* out = (float*)d_out;

    if (ws_size < 4653056) return;  // diagnostic guard (poison signature if too small)

    char* ws = (char*)d_ws;
    // layout (total 4,653,056 B, < round-1 proven 5,046,272):
    // WT[384K bf16 x3] | M8[64K fp32] | Qb[2M bf16] | pMb[2M bf16]
    unsigned short* WT  = (unsigned short*)(ws);
    float* M8           = (float*)(ws + 393216);
    unsigned short* Qb  = (unsigned short*)(ws + 458752);
    unsigned short* pMb = (unsigned short*)(ws + 2555904);

    prep_w3<<<256, 256, 0, stream>>>(Wk, Wv, Wq, WT);
    kv_moment10<<<256, 768, 0, stream>>>(x, WT, pMb, Qb);
    reduce_m8<<<64, 256, 0, stream>>>(pMb, M8);
    final_qm<<<256, 256, 0, stream>>>(Qb, M8, out);
}